// Round 6
// baseline (364.577 us; speedup 1.0000x reference)
//
#include <hip/hip_runtime.h>

#define T_HORIZON 50
#define NU 4
#define NY 4
#define KH 32
#define NW (8*KH + KH + KH + 1)   // Wh(256) + bh(32) + Wo(32) + bo(1) = 321
#define BPB 64                    // batch elements per block (4 waves x 16)

__device__ __forceinline__ float fast_tanh(float v) {
    // tanh(v) = 1 - 2/(exp(2v)+1); identical to the round-2/4 passing kernels.
    float e = __builtin_amdgcn_exp2f(v * 2.88539008177792681472f);
    float r = __builtin_amdgcn_rcpf(e + 1.0f);
    return fmaf(-2.0f, r, 1.0f);
}

__global__ __launch_bounds__(256, 3) void rollout_kernel(
    const float* __restrict__ u,    // (B, 50, 4)
    const float* __restrict__ y0g,  // (B, 4)
    const float* __restrict__ Whg,  // (8, 32)
    const float* __restrict__ bhg,  // (32)
    const float* __restrict__ Wog,  // (32, 1)
    const float* __restrict__ bog,  // (1)
    float* __restrict__ out)        // (B, 50, 1)
{
    __shared__ float sW[NW];
    __shared__ __align__(16) float sOut[BPB * T_HORIZON];  // [b_local][t]
    const int tid = threadIdx.x;

    if (tid < 8*KH) sW[tid] = Whg[tid];
    if (tid < 65) {
        float v;
        if (tid < KH)        v = bhg[tid];
        else if (tid < 2*KH) v = Wog[tid - KH];
        else                 v = bog[0];
        sW[8*KH + tid] = v;
    }
    __syncthreads();

    const int lane = tid & 63;
    const int widx = tid >> 6;
    const int bsub = lane & 15;
    const int jg   = lane >> 4;      // mod-4 class: lane owns j = jg + 4k, k=0..7
    const int bl   = widx * 16 + bsub;
    const int b    = blockIdx.x * BPB + bl;

    // Per-lane scalar weight copies for its 8 owned j's (j = jg + 4k, k asc.,
    // identical accumulation order to the round-2/4 passing kernels).
    float wh[8][8];   // [i][k]
    float bh[8], wor[8];
#pragma unroll
    for (int i = 0; i < 8; ++i)
#pragma unroll
        for (int k = 0; k < 8; ++k)
            wh[i][k] = sW[i*KH + jg + 4*k];
#pragma unroll
    for (int k = 0; k < 8; ++k) {
        bh[k]  = sW[8*KH + jg + 4*k];
        wor[k] = sW[9*KH + jg + 4*k];
    }
    float bor = sW[10*KH];

    // Pin every weight in a VGPR: asm-defined scalars (32-bit, no pair-
    // alignment hazard, no instruction emitted) cannot be rematerialized
    // from LDS inside the t-loop.
#pragma unroll
    for (int i = 0; i < 8; ++i)
#pragma unroll
        for (int k = 0; k < 8; ++k)
            asm volatile("" : "+v"(wh[i][k]));
#pragma unroll
    for (int k = 0; k < 8; ++k) {
        asm volatile("" : "+v"(bh[k]));
        asm volatile("" : "+v"(wor[k]));
    }
    asm volatile("" : "+v"(bor));

    const float4* ub = (const float4*)(u + (size_t)b * T_HORIZON * NU);
    float4 yv = *(const float4*)(y0g + (size_t)b * NY);
    float y1 = yv.x, y2 = yv.y, y3 = yv.z, y4 = yv.w;

    float4 un = ub[0];
    for (int t = 0; t < T_HORIZON; ++t) {
        float4 uc = un;
        if (t + 1 < T_HORIZON) un = ub[t + 1];

        // 8 independent pre-activation chains, element order: bh, u0..u3, y1..y4
        float aa[8];
#pragma unroll
        for (int k = 0; k < 8; ++k) {
            float a = fmaf(uc.x, wh[0][k], bh[k]);
            a = fmaf(uc.y, wh[1][k], a);
            a = fmaf(uc.z, wh[2][k], a);
            a = fmaf(uc.w, wh[3][k], a);
            a = fmaf(y1,   wh[4][k], a);
            a = fmaf(y2,   wh[5][k], a);
            a = fmaf(y3,   wh[6][k], a);
            a = fmaf(y4,   wh[7][k], a);
            aa[k] = a;
        }

        // serial class accumulation, verbatim round-2 statement forms
        float pcls = 0.0f;
#pragma unroll
        for (int k = 0; k < 8; ++k) {
            float m = fast_tanh(aa[k]) * wor[k];
            pcls += m;
        }

        // (pA+pB)+(pC+pD) exactly (IEEE add commutative -> all lanes bitwise equal)
        float partial = pcls;
        partial += __shfl_xor(partial, 16, 64);
        partial += __shfl_xor(partial, 32, 64);
        float pred = bor + partial;

        if (jg == 0) sOut[bl * T_HORIZON + t] = pred;

        y4 = y3; y3 = y2; y2 = y1; y1 = pred;
    }
    __syncthreads();

    // Coalesced flush: block's out region is contiguous 64*50 floats.
    const float4* s4 = (const float4*)sOut;
    float4* o4 = (float4*)(out + (size_t)blockIdx.x * BPB * T_HORIZON);
#pragma unroll
    for (int k = 0; k < 4; ++k) {
        int idx = k * 256 + tid;
        if (idx < (BPB * T_HORIZON) / 4) o4[idx] = s4[idx];
    }
}

extern "C" void kernel_launch(void* const* d_in, const int* in_sizes, int n_in,
                              void* d_out, int out_size, void* d_ws, size_t ws_size,
                              hipStream_t stream) {
    const float* u   = (const float*)d_in[0];
    const float* y0g = (const float*)d_in[1];
    const float* Whg = (const float*)d_in[2];
    const float* bhg = (const float*)d_in[3];
    const float* Wog = (const float*)d_in[4];
    const float* bog = (const float*)d_in[5];
    float* out = (float*)d_out;

    const int B = in_sizes[1] / NY;          // 524288
    dim3 grid(B / BPB), block(256);
    rollout_kernel<<<grid, block, 0, stream>>>(u, y0g, Whg, bhg, Wog, bog, out);
}

// Round 7
// 335.079 us; speedup vs baseline: 1.0880x; 1.0880x over previous
//
#include <hip/hip_runtime.h>

#define T_HORIZON 50
#define NU 4
#define NY 4
#define KH 32
#define BPB 64                    // batch elements per block (each wave: all 64)

typedef float v2f __attribute__((ext_vector_type(2)));

__device__ __forceinline__ v2f fma2(v2f a, v2f b, v2f c) {
    return __builtin_elementwise_fma(a, b, c);   // per-element IEEE fma
}

#define TANH_SCALE 2.88539008177792681472f

// Stage transposed weights into d_ws: ws[jg][i][k] = W_all[i][jg + 4k]
// i=0..7: Wh rows; i=8: bh; i=9: wor. 4*10*8 = 320 floats.
// Pair (k=2p, 2p+1) is 8B-contiguous -> s_load_dwordx2 in the main kernel.
__global__ void stage_weights(const float* __restrict__ Whg,
                              const float* __restrict__ bhg,
                              const float* __restrict__ Wog,
                              float* __restrict__ ws) {
    int idx = threadIdx.x;
    if (idx < 320) {
        int jg = idx / 80, r = idx % 80, i = r / 8, k = r % 8;
        int j = jg + 4 * k;
        float v = (i < 8) ? Whg[i * KH + j] : (i == 8 ? bhg[j] : Wog[j]);
        ws[idx] = v;
    }
}

__global__ __launch_bounds__(256, 6) void rollout_kernel(
    const float* __restrict__ u,    // (B, 50, 4)
    const float* __restrict__ y0g,  // (B, 4)
    const float* __restrict__ bog,  // (1)
    const float* __restrict__ wsW,  // (4, 10, 8) staged
    float* __restrict__ out)        // (B, 50, 1)
{
    __shared__ __align__(16) float sOut[BPB * T_HORIZON];  // [b_local][t]
    __shared__ float sRed[2][4][BPB];                      // dbuf class partials

    const int tid  = threadIdx.x;
    const int lane = tid & 63;
    // wave's j-class, forced wave-uniform so weight loads become s_load
    const int jg = __builtin_amdgcn_readfirstlane(tid >> 6);

    const float* wb = wsW + jg * 80;   // uniform base
    // Wave-uniform weight pairs -> SGPR pairs (consumed directly by pk_fma).
    v2f wh2[8][4], wor2[4];
#pragma unroll
    for (int i = 0; i < 8; ++i)
#pragma unroll
        for (int p = 0; p < 4; ++p)
            wh2[i][p] = *(const v2f*)(wb + i * 8 + 2 * p);
#pragma unroll
    for (int p = 0; p < 4; ++p)
        wor2[p] = *(const v2f*)(wb + 9 * 8 + 2 * p);
    const float bor = bog[0];          // uniform -> SGPR

    // bh must be the VGPR operand of the first pk_fma (only 1 SGPR src/instr):
    // load as scalars and pin each in a VGPR (32-bit pins, proven safe in r6).
    float bhs[8];
#pragma unroll
    for (int k = 0; k < 8; ++k) bhs[k] = wb[8 * 8 + k];
#pragma unroll
    for (int k = 0; k < 8; ++k) asm volatile("" : "+v"(bhs[k]));
    v2f bh2[4];
#pragma unroll
    for (int p = 0; p < 4; ++p) bh2[p] = v2f{bhs[2 * p], bhs[2 * p + 1]};

    const v2f scale2 = {TANH_SCALE, TANH_SCALE};
    const v2f one2   = {1.0f, 1.0f};
    const v2f ntwo2  = {-2.0f, -2.0f};

    // Each wave handles ALL 64 batch elements of the block (redundant y-state
    // across the 4 waves; weights differ per wave).
    const int b = blockIdx.x * BPB + lane;
    const float4* ub = (const float4*)(u + (size_t)b * T_HORIZON * NU);
    float4 yv = *(const float4*)(y0g + (size_t)b * NY);
    float y1 = yv.x, y2 = yv.y, y3 = yv.z, y4 = yv.w;

    float4 un = ub[0];
    for (int t = 0; t < T_HORIZON; ++t) {
        float4 uc = un;
        if (t + 1 < T_HORIZON) un = ub[t + 1];

        v2f ux = {uc.x, uc.x}, uy = {uc.y, uc.y}, uz = {uc.z, uc.z}, uw = {uc.w, uc.w};
        v2f p1 = {y1, y1}, p2 = {y2, y2}, p3 = {y3, y3}, p4 = {y4, y4};

        float pcls = 0.0f;
#pragma unroll
        for (int p = 0; p < 4; ++p) {
            // identical element order to rounds 2/4/6: bh, u0..u3, y1..y4
            v2f a = fma2(ux, wh2[0][p], bh2[p]);
            a = fma2(uy, wh2[1][p], a);
            a = fma2(uz, wh2[2][p], a);
            a = fma2(uw, wh2[3][p], a);
            a = fma2(p1, wh2[4][p], a);
            a = fma2(p2, wh2[5][p], a);
            a = fma2(p3, wh2[6][p], a);
            a = fma2(p4, wh2[7][p], a);

            // tanh cluster, per-element identical to round 4:
            v2f s = a * scale2;
            float e0 = __builtin_amdgcn_exp2f(s.x);
            float e1 = __builtin_amdgcn_exp2f(s.y);
            v2f ep = v2f{e0, e1} + one2;
            v2f r  = {__builtin_amdgcn_rcpf(ep.x), __builtin_amdgcn_rcpf(ep.y)};
            v2f th = fma2(ntwo2, r, one2);
            v2f m  = th * wor2[p];
            pcls += m.x;   // k=2p   (j = jg+8p)
            pcls += m.y;   // k=2p+1 (j = jg+8p+4)
        }

        // Cross-wave class reduce: double-buffered, ONE barrier per step.
        const int buf = t & 1;
        sRed[buf][jg][lane] = pcls;
        __syncthreads();
        float c0 = sRed[buf][0][lane];
        float c1 = sRed[buf][1][lane];
        float c2 = sRed[buf][2][lane];
        float c3 = sRed[buf][3][lane];
        // same grouping as shfl_xor(16)+(32): (c0+c1)+(c2+c3)
        float partial = (c0 + c1) + (c2 + c3);
        float pred = bor + partial;

        if (jg == 0) sOut[lane * T_HORIZON + t] = pred;

        y4 = y3; y3 = y2; y2 = y1; y1 = pred;
    }
    __syncthreads();

    // Coalesced flush: block's out region is contiguous 64*50 floats.
    const float4* s4 = (const float4*)sOut;
    float4* o4 = (float4*)(out + (size_t)blockIdx.x * BPB * T_HORIZON);
#pragma unroll
    for (int k = 0; k < 4; ++k) {
        int idx = k * 256 + tid;
        if (idx < (BPB * T_HORIZON) / 4) o4[idx] = s4[idx];
    }
}

extern "C" void kernel_launch(void* const* d_in, const int* in_sizes, int n_in,
                              void* d_out, int out_size, void* d_ws, size_t ws_size,
                              hipStream_t stream) {
    const float* u   = (const float*)d_in[0];
    const float* y0g = (const float*)d_in[1];
    const float* Whg = (const float*)d_in[2];
    const float* bhg = (const float*)d_in[3];
    const float* Wog = (const float*)d_in[4];
    const float* bog = (const float*)d_in[5];
    float* out = (float*)d_out;
    float* ws  = (float*)d_ws;    // 320 floats staged weights

    stage_weights<<<1, 320, 0, stream>>>(Whg, bhg, Wog, ws);

    const int B = in_sizes[1] / NY;          // 524288
    dim3 grid(B / BPB), block(256);
    rollout_kernel<<<grid, block, 0, stream>>>(u, y0g, bog, ws, out);
}